// Round 1
// baseline (1184.947 us; speedup 1.0000x reference)
//
#include <hip/hip_runtime.h>
#include <math.h>

#define K_CB 2
#define DIM 128
#define NEMB 4096
#define NB 32
#define HW 1024
#define NPK 32768          // NB*HW vectors per codebook
#define CCH 256            // channels in x
#define TN 64              // n-tile per block
#define TJ 256             // j-chunk
#define DSLAB 16           // d-slab staged for B

// ---------------- zero scratch (hist + diff partials) ----------------
__global__ void k_zero(int* __restrict__ hist, float* __restrict__ diffp) {
    int t = blockIdx.x * blockDim.x + threadIdx.x;
    if (t < K_CB * NEMB) { hist[t] = 0; diffp[t] = 0.f; }
}

// ---------------- ||e_j||^2 per (k,j) ----------------
__global__ void k_enorm(const float* __restrict__ embed, float* __restrict__ enorm) {
    int g = blockIdx.x * blockDim.x + threadIdx.x;   // 0..8191
    int k = g >> 12;
    int j = g & (NEMB - 1);
    const float* e = embed + (size_t)k * DIM * NEMB + j;
    float s = 0.f;
#pragma unroll 8
    for (int d = 0; d < DIM; ++d) {
        float v = e[(size_t)d * NEMB];
        s = fmaf(v, v, s);
    }
    enorm[g] = s;
}

// ---------------- main: fp32 GEMM-score + argmin ----------------
// block = 64 n (one b, contiguous hw) x all 4096 j for one codebook.
// A-tile [128 d][64 n] resident in LDS for all 16 j-chunks.
// score(n,j) = ||e_j||^2 - 2 f_n . e_j   (||f||^2 omitted: constant per n)
__launch_bounds__(256)
__global__ void k_argmin(const float* __restrict__ x, const float* __restrict__ embed,
                         const float* __restrict__ enorm, int* __restrict__ idx_out,
                         float* __restrict__ argf, int* __restrict__ hist)
{
    __shared__ float As[DIM][TN];     // 32 KB
    __shared__ float Bs[DSLAB][TJ];   // 16 KB
    const int blk = blockIdx.x;       // 0..1023
    const int k = blk >> 9;
    const int n0 = (blk & 511) * TN;
    const int b = n0 >> 10;
    const int hw0 = n0 & (HW - 1);
    const int tid = threadIdx.x;

    // x[b][k*128 + d][hw0 + n] : contiguous in n for fixed d -> coalesced
    const float* xk = x + ((size_t)b * CCH + (size_t)k * DIM) * HW + hw0;
    for (int i = tid; i < DIM * TN; i += 256) {
        int d = i >> 6;
        int n = i & 63;
        As[d][n] = xk[(size_t)d * HW + n];
    }

    const int tn = tid >> 5;   // 0..7 : owns n = n0 + tn*8 .. +7
    const int tj = tid & 31;   // 0..31: j lanes
    const float* ek = embed + (size_t)k * DIM * NEMB;
    const float* enk = enorm + k * NEMB;

    float best[8];
    int bestj[8];
#pragma unroll
    for (int i = 0; i < 8; ++i) { best[i] = 3.4e38f; bestj[i] = 0; }

    for (int jc = 0; jc < NEMB / TJ; ++jc) {
        const int j0 = jc * TJ;
        float acc[8][8];
#pragma unroll
        for (int i = 0; i < 8; ++i)
#pragma unroll
            for (int jl = 0; jl < 8; ++jl) acc[i][jl] = 0.f;

        for (int ds = 0; ds < DIM / DSLAB; ++ds) {
            __syncthreads();   // previous Bs reads done (also covers initial As fill)
            for (int i = tid; i < DSLAB * TJ; i += 256) {
                int d = i >> 8;
                int j = i & (TJ - 1);
                Bs[d][j] = ek[(size_t)(ds * DSLAB + d) * NEMB + j0 + j];
            }
            __syncthreads();
#pragma unroll
            for (int d = 0; d < DSLAB; ++d) {
                float a[8], bb[8];
#pragma unroll
                for (int i = 0; i < 8; ++i) a[i] = As[ds * DSLAB + d][tn * 8 + i];
                // j micro-layout: pairs (float2) strided by 64 -> ds_read_b64, 2-way (free) aliasing
#pragma unroll
                for (int jl = 0; jl < 8; ++jl) bb[jl] = Bs[d][(jl >> 1) * 64 + tj * 2 + (jl & 1)];
#pragma unroll
                for (int i = 0; i < 8; ++i)
#pragma unroll
                    for (int jl = 0; jl < 8; ++jl)
                        acc[i][jl] = fmaf(a[i], bb[jl], acc[i][jl]);
            }
        }
        // epilogue: score + running argmin (first-index tie-break)
#pragma unroll
        for (int jl = 0; jl < 8; ++jl) {
            const int j = j0 + (jl >> 1) * 64 + tj * 2 + (jl & 1);
            const float en = enk[j];
#pragma unroll
            for (int i = 0; i < 8; ++i) {
                float s = fmaf(-2.f, acc[i][jl], en);
                if (s < best[i] || (s == best[i] && j < bestj[i])) { best[i] = s; bestj[i] = j; }
            }
        }
    }

    // reduce over the 32 lanes (same tn group) — xor masks <32 stay within half-wave
#pragma unroll
    for (int off = 1; off < 32; off <<= 1) {
#pragma unroll
        for (int i = 0; i < 8; ++i) {
            float ob = __shfl_xor(best[i], off);
            int oj = __shfl_xor(bestj[i], off);
            if (ob < best[i] || (ob == best[i] && oj < bestj[i])) { best[i] = ob; bestj[i] = oj; }
        }
    }
    if (tj == 0) {
        const int base = k * NPK + n0 + tn * 8;
#pragma unroll
        for (int i = 0; i < 8; ++i) {
            idx_out[base + i] = bestj[i];
            argf[base + i] = (float)bestj[i];
            atomicAdd(&hist[k * NEMB + bestj[i]], 1);
        }
    }
}

// ---------------- gather z_q + diff partial sums ----------------
// block = (k, b, d): one channel row of 1024 hw. Coalesced x read / zq write,
// e-row gather is L1/L2-resident (2 MB per codebook).
__global__ void k_gather(const float* __restrict__ x, const float* __restrict__ embed,
                         const int* __restrict__ idx, float* __restrict__ zq,
                         float* __restrict__ diffp)
{
    const int blk = blockIdx.x;           // k*4096 + b*128 + d
    const int k = blk >> 12;
    const int b = (blk >> 7) & 31;
    const int d = blk & 127;
    const float* erow = embed + ((size_t)k * DIM + d) * NEMB;
    const int* idxr = idx + k * NPK + b * HW;
    const size_t row = ((size_t)b * CCH + (size_t)k * DIM + d) * HW;
    const float* xr = x + row;
    float* zr = zq + row;
    const int t = threadIdx.x;
    float s = 0.f;
    for (int h = t; h < HW; h += 256) {
        int j = idxr[h];
        float q = erow[j];
        float xv = xr[h];
        float df = q - xv;
        s = fmaf(df, df, s);
        zr[h] = q;
    }
    __shared__ float red[256];
    red[t] = s;
    __syncthreads();
    for (int off = 128; off > 0; off >>= 1) {
        if (t < off) red[t] += red[t + off];
        __syncthreads();
    }
    if (t == 0) diffp[blk] = red[0];
}

// ---------------- finalize diffs + perplexity ----------------
__global__ void k_final(const float* __restrict__ diffp, const int* __restrict__ hist,
                        float* __restrict__ diffs, float* __restrict__ ppls)
{
    const int k = blockIdx.x;
    const int t = threadIdx.x;
    __shared__ float red[256];
    float s = 0.f;
    for (int i = t; i < NEMB; i += 256) s += diffp[k * NEMB + i];
    red[t] = s;
    __syncthreads();
    for (int off = 128; off > 0; off >>= 1) {
        if (t < off) red[t] += red[t + off];
        __syncthreads();
    }
    if (t == 0) diffs[k] = red[0] / (float)((size_t)NPK * DIM);
    __syncthreads();
    float s2 = 0.f;
    for (int i = t; i < NEMB; i += 256) {
        float p = (float)hist[k * NEMB + i] * (1.0f / (float)NPK);
        s2 += p * logf(p + 1e-10f);
    }
    red[t] = s2;
    __syncthreads();
    for (int off = 128; off > 0; off >>= 1) {
        if (t < off) red[t] += red[t + off];
        __syncthreads();
    }
    if (t == 0) ppls[k] = expf(-red[0]);
}

extern "C" void kernel_launch(void* const* d_in, const int* in_sizes, int n_in,
                              void* d_out, int out_size, void* d_ws, size_t ws_size,
                              hipStream_t stream) {
    const float* x = (const float*)d_in[0];       // [32,256,32,32]
    const float* embed = (const float*)d_in[1];   // [2,128,4096]
    float* out = (float*)d_out;
    float* zq    = out;                 // 8388608
    float* diffs = out + 8388608;       // 2
    float* argf  = out + 8388610;       // 65536 ([K,B,H,W] as float)
    float* ppls  = out + 8454146;       // 2

    float* ws = (float*)d_ws;
    float* enorm = ws;                               // [2][4096]
    int*   idx   = (int*)(ws + 8192);                // [2][32768]
    int*   hist  = (int*)(ws + 8192 + 65536);        // [2][4096]
    float* diffp = ws + 8192 + 65536 + 8192;         // [2][4096]

    k_zero  <<<32,   256, 0, stream>>>(hist, diffp);
    k_enorm <<<32,   256, 0, stream>>>(embed, enorm);
    k_argmin<<<1024, 256, 0, stream>>>(x, embed, enorm, idx, argf, hist);
    k_gather<<<8192, 256, 0, stream>>>(x, embed, idx, zq, diffp);
    k_final <<<2,    256, 0, stream>>>(diffp, hist, diffs, ppls);
}

// Round 3
// 532.859 us; speedup vs baseline: 2.2238x; 2.2238x over previous
//
#include <hip/hip_runtime.h>
#include <hip/hip_bf16.h>
#include <math.h>

#define K_CB 2
#define DIM 128
#define NEMB 4096
#define HW 1024
#define NPK 32768
#define CCH 256
#define MARGIN 0.45f

typedef __attribute__((ext_vector_type(8))) short short8;
typedef __attribute__((ext_vector_type(4))) float f32x4;

// ---------------- zero scratch ----------------
__global__ void k_zero(int* __restrict__ hist, float* __restrict__ diffp, int* __restrict__ cnt) {
    int t = blockIdx.x * blockDim.x + threadIdx.x;
    if (t < K_CB * NEMB) { hist[t] = 0; diffp[t] = 0.f; }
    if (t < K_CB) cnt[t] = 0;
}

// ---------------- ||e_j||^2 per (k,j) (fp32) ----------------
__global__ void k_enorm(const float* __restrict__ embed, float* __restrict__ enorm) {
    int g = blockIdx.x * blockDim.x + threadIdx.x;   // 0..8191
    int k = g >> 12;
    int j = g & (NEMB - 1);
    const float* e = embed + (size_t)k * DIM * NEMB + j;
    float s = 0.f;
#pragma unroll 8
    for (int d = 0; d < DIM; ++d) {
        float v = e[(size_t)d * NEMB];
        s = fmaf(v, v, s);
    }
    enorm[g] = s;
}

// ---------------- transpose embed -> bf16 [k][j][d] ----------------
__global__ void k_prep_e(const float* __restrict__ embed, ushort* __restrict__ ebf) {
    __shared__ ushort tile[DIM][130];
    const int k = blockIdx.x >> 5;
    const int j0 = (blockIdx.x & 31) * 128;
    const int t = threadIdx.x;
    const float* ek = embed + (size_t)k * DIM * NEMB;
    for (int i = 0; i < 64; ++i) {
        int idx = i * 256 + t;
        int d = idx >> 7, jj = idx & 127;
        float v = ek[(size_t)d * NEMB + j0 + jj];
        __hip_bfloat16 h = __float2bfloat16(v);
        tile[d][jj] = *(ushort*)&h;
    }
    __syncthreads();
    ushort* outk = ebf + ((size_t)k * NEMB + j0) * DIM;
    for (int i = 0; i < 64; ++i) {
        int idx = i * 256 + t;
        int jj = idx >> 7, d = idx & 127;
        outk[(size_t)jj * DIM + d] = tile[d][jj];
    }
}

// ---------------- coarse bf16 MFMA scoring + best/second argmin ----------------
// block: (k, n-tile of 128). 4 waves; wave w owns rows [w*32, w*32+32) and the
// FULL 128-col j-tile (no cross-wave row sharing -> single writer per row).
// LDS tiles XOR-swizzled (ushort idx ^= (row&7)<<3 == byte ^ (row&7)<<4).
__launch_bounds__(256, 2)
__global__ void k_score(const float* __restrict__ x, const ushort* __restrict__ ebf,
                        const float* __restrict__ enorm, int* __restrict__ idxw,
                        int* __restrict__ list, int* __restrict__ cnt)
{
    __shared__ __align__(16) ushort As[128 * 128];
    __shared__ __align__(16) ushort Bs[128 * 128];
    const int blk = blockIdx.x;
    const int k = blk >> 8;
    const int n0 = (blk & 255) * 128;
    const int b = n0 >> 10;
    const int hw0 = n0 & (HW - 1);
    const int t = threadIdx.x;
    const int lane = t & 63;
    const int w = t >> 6;            // wave id: owns rows w*32..w*32+31
    const int l15 = lane & 15, l4 = lane >> 4;

    // ---- stage A once: transpose x[d][hw] -> As[n'][d] bf16, swizzled ----
    const float* xk = x + ((size_t)(b * CCH + k * DIM)) * HW + hw0;
    for (int i = 0; i < 64; ++i) {
        int idx = i * 256 + t;
        int d = idx >> 7, h = idx & 127;
        float v = xk[(size_t)d * HW + h];
        __hip_bfloat16 hb = __float2bfloat16(v);
        As[h * 128 + (d ^ ((h & 7) << 3))] = *(ushort*)&hb;
    }

    const ushort* ebk = ebf + (size_t)k * NEMB * DIM;
    const float* enk = enorm + k * NEMB;

    float best[8], second[8];
    int bestj[8];
#pragma unroll
    for (int i = 0; i < 8; ++i) { best[i] = 3.4e38f; second[i] = 3.4e38f; bestj[i] = 0; }

    for (int jt = 0; jt < 32; ++jt) {
        const int j0 = jt * 128;
        __syncthreads();   // previous tile's reads done (also covers A-stage at jt=0)
        // ---- stage B tile [j'][d] via global_load_lds, inverse-swizzled source ----
#pragma unroll
        for (int it = 0; it < 8; ++it) {
            int lin = (it * 256 + t) * 16;         // dest byte in Bs (linear)
            int row = lin >> 8;                    // j'
            int col = lin & 255;
            int src = row * 256 + (col ^ ((row & 7) << 4));
            const char* g = (const char*)ebk + (size_t)j0 * 256 + src;
            char* lds = (char*)(&Bs[0]) + (it * 256 + (t & ~63)) * 16;  // wave-uniform base
            __builtin_amdgcn_global_load_lds(
                (const __attribute__((address_space(1))) unsigned int*)g,
                (__attribute__((address_space(3))) unsigned int*)lds, 16, 0, 0);
        }
        __syncthreads();

        // ---- compute this wave's 32 rows x 128 cols ----
        f32x4 acc[2][8];
#pragma unroll
        for (int mf = 0; mf < 2; ++mf)
#pragma unroll
            for (int jf = 0; jf < 8; ++jf) acc[mf][jf] = (f32x4){0.f, 0.f, 0.f, 0.f};

#pragma unroll
        for (int kk = 0; kk < 4; ++kk) {
            short8 a[2], bb[8];
#pragma unroll
            for (int mf = 0; mf < 2; ++mf) {
                int row = w * 32 + mf * 16 + l15;
                int ci = (kk * 32 + l4 * 8) ^ ((row & 7) << 3);
                a[mf] = *(const short8*)&As[row * 128 + ci];
            }
#pragma unroll
            for (int jf = 0; jf < 8; ++jf) {
                int row = jf * 16 + l15;
                int ci = (kk * 32 + l4 * 8) ^ ((row & 7) << 3);
                bb[jf] = *(const short8*)&Bs[row * 128 + ci];
            }
#pragma unroll
            for (int mf = 0; mf < 2; ++mf)
#pragma unroll
                for (int jf = 0; jf < 8; ++jf)
                    acc[mf][jf] = __builtin_amdgcn_mfma_f32_16x16x32_bf16(a[mf], bb[jf], acc[mf][jf], 0, 0, 0);
        }

        // ---- epilogue: score + best/second tracking over the FULL j-tile ----
#pragma unroll
        for (int jf = 0; jf < 8; ++jf) {
            const int j = j0 + jf * 16 + l15;
            const float en = enk[j];
#pragma unroll
            for (int mf = 0; mf < 2; ++mf) {
#pragma unroll
                for (int r = 0; r < 4; ++r) {
                    float s = fmaf(-2.f, acc[mf][jf][r], en);
                    int ti = mf * 4 + r;
                    float mx = fmaxf(s, best[ti]);
                    second[ti] = fminf(second[ti], mx);
                    bool lt = s < best[ti];
                    bestj[ti] = lt ? j : bestj[ti];
                    best[ti] = lt ? s : best[ti];
                }
            }
        }
    }

    // ---- merge across the 16 j-lanes (same rows: same w, same l4) ----
#pragma unroll
    for (int off = 1; off < 16; off <<= 1) {
#pragma unroll
        for (int ti = 0; ti < 8; ++ti) {
            float ob = __shfl_xor(best[ti], off);
            float os = __shfl_xor(second[ti], off);
            int oj = __shfl_xor(bestj[ti], off);
            float ns = fminf(fmaxf(best[ti], ob), fminf(second[ti], os));
            bool take = (ob < best[ti]) || (ob == best[ti] && oj < bestj[ti]);
            bestj[ti] = take ? oj : bestj[ti];
            best[ti] = fminf(best[ti], ob);
            second[ti] = ns;
        }
    }
    if (l15 == 0) {
#pragma unroll
        for (int ti = 0; ti < 8; ++ti) {
            int mf = ti >> 2, r = ti & 3;
            int n = n0 + w * 32 + mf * 16 + l4 * 4 + r;
            int gidx = k * NPK + n;
            idxw[gidx] = bestj[ti];
            if (second[ti] - best[ti] < MARGIN) {
                int p = atomicAdd(&cnt[k], 1);
                list[k * NPK + p] = gidx;
            }
        }
    }
}

// ---------------- exact fp32 rescore of flagged rows (8 rows/chunk) ----------------
__global__ void k_rescore(const float* __restrict__ x, const float* __restrict__ embed,
                          const float* __restrict__ enorm, const int* __restrict__ list,
                          const int* __restrict__ cnt, int* __restrict__ idxw)
{
    __shared__ float xr[8][128];
    __shared__ float rs[8][256];
    __shared__ int rj[8][256];
    const int bk = blockIdx.x & 1;
    const int t = threadIdx.x;
    const int ck = cnt[bk];
    const int nch = (ck + 7) >> 3;
    for (int c = blockIdx.x >> 1; c < nch; c += (gridDim.x >> 1)) {
        const int base = c * 8;
        const int cn = min(8, ck - base);
        __syncthreads();   // xr reuse safety
        for (int ii = t; ii < cn * 128; ii += 256) {
            int ri = ii >> 7, d = ii & 127;
            int gidx = list[bk * NPK + base + ri];
            int n = gidx & (NPK - 1);
            int bb = n >> 10, hw = n & 1023;
            xr[ri][d] = x[((size_t)(bb * CCH + bk * DIM + d)) * HW + hw];
        }
        __syncthreads();
        float bb8[8]; int bj8[8];
#pragma unroll
        for (int ri = 0; ri < 8; ++ri) { bb8[ri] = 3.4e38f; bj8[ri] = 0; }
        for (int jj = 0; jj < 16; ++jj) {
            const int j = jj * 256 + t;
            float dot[8];
#pragma unroll
            for (int ri = 0; ri < 8; ++ri) dot[ri] = 0.f;
            const float* ek = embed + (size_t)bk * DIM * NEMB + j;
            for (int d = 0; d < DIM; ++d) {
                float ev = ek[(size_t)d * NEMB];
#pragma unroll
                for (int ri = 0; ri < 8; ++ri) dot[ri] = fmaf(xr[ri][d], ev, dot[ri]);
            }
            const float en = enorm[bk * NEMB + j];
#pragma unroll
            for (int ri = 0; ri < 8; ++ri) {
                float s = fmaf(-2.f, dot[ri], en);
                if (s < bb8[ri]) { bb8[ri] = s; bj8[ri] = j; }
            }
        }
#pragma unroll
        for (int ri = 0; ri < 8; ++ri) { rs[ri][t] = bb8[ri]; rj[ri][t] = bj8[ri]; }
        __syncthreads();
        for (int off = 128; off > 0; off >>= 1) {
            if (t < off) {
#pragma unroll
                for (int ri = 0; ri < 8; ++ri) {
                    float o = rs[ri][t + off]; int oj = rj[ri][t + off];
                    if (o < rs[ri][t] || (o == rs[ri][t] && oj < rj[ri][t])) { rs[ri][t] = o; rj[ri][t] = oj; }
                }
            }
            __syncthreads();
        }
        if (t < cn) idxw[list[bk * NPK + base + t]] = rj[t][0];
    }
}

// ---------------- idx -> argf float + histogram ----------------
__global__ void k_emit(const int* __restrict__ idxw, float* __restrict__ argf, int* __restrict__ hist) {
    int g = blockIdx.x * 256 + threadIdx.x;
    int j = idxw[g];
    argf[g] = (float)j;
    atomicAdd(&hist[(g >> 15) * NEMB + j], 1);
}

// ---------------- gather z_q + diff partial sums ----------------
__global__ void k_gather(const float* __restrict__ x, const float* __restrict__ embed,
                         const int* __restrict__ idx, float* __restrict__ zq,
                         float* __restrict__ diffp)
{
    const int blk = blockIdx.x;           // k*4096 + b*128 + d
    const int k = blk >> 12;
    const int b = (blk >> 7) & 31;
    const int d = blk & 127;
    const float* erow = embed + ((size_t)k * DIM + d) * NEMB;
    const int* idxr = idx + k * NPK + b * HW;
    const size_t row = ((size_t)b * CCH + (size_t)k * DIM + d) * HW;
    const float* xr = x + row;
    float* zr = zq + row;
    const int t = threadIdx.x;
    float s = 0.f;
    for (int h = t; h < HW; h += 256) {
        int j = idxr[h];
        float q = erow[j];
        float xv = xr[h];
        float df = q - xv;
        s = fmaf(df, df, s);
        zr[h] = q;
    }
    __shared__ float red[256];
    red[t] = s;
    __syncthreads();
    for (int off = 128; off > 0; off >>= 1) {
        if (t < off) red[t] += red[t + off];
        __syncthreads();
    }
    if (t == 0) diffp[blk] = red[0];
}

// ---------------- finalize diffs + perplexity ----------------
__global__ void k_final(const float* __restrict__ diffp, const int* __restrict__ hist,
                        float* __restrict__ diffs, float* __restrict__ ppls)
{
    const int k = blockIdx.x;
    const int t = threadIdx.x;
    __shared__ float red[256];
    float s = 0.f;
    for (int i = t; i < NEMB; i += 256) s += diffp[k * NEMB + i];
    red[t] = s;
    __syncthreads();
    for (int off = 128; off > 0; off >>= 1) {
        if (t < off) red[t] += red[t + off];
        __syncthreads();
    }
    if (t == 0) diffs[k] = red[0] / (float)((size_t)NPK * DIM);
    __syncthreads();
    float s2 = 0.f;
    for (int i = t; i < NEMB; i += 256) {
        float p = (float)hist[k * NEMB + i] * (1.0f / (float)NPK);
        s2 += p * logf(p + 1e-10f);
    }
    red[t] = s2;
    __syncthreads();
    for (int off = 128; off > 0; off >>= 1) {
        if (t < off) red[t] += red[t + off];
        __syncthreads();
    }
    if (t == 0) ppls[k] = expf(-red[0]);
}

extern "C" void kernel_launch(void* const* d_in, const int* in_sizes, int n_in,
                              void* d_out, int out_size, void* d_ws, size_t ws_size,
                              hipStream_t stream) {
    const float* x = (const float*)d_in[0];       // [32,256,32,32]
    const float* embed = (const float*)d_in[1];   // [2,128,4096]
    float* out = (float*)d_out;
    float* zq    = out;                 // 8388608
    float* diffs = out + 8388608;       // 2
    float* argf  = out + 8388610;       // 65536 ([K,B,H,W] as float)
    float* ppls  = out + 8454146;       // 2

    char* W = (char*)d_ws;
    ushort* ebf  = (ushort*)W;                     // 2,097,152 B : embedT bf16 [2][4096][128]
    float* enorm = (float*)(W + 2097152);          // 32768 B
    int*   idx   = (int*)(W + 2129920);            // 262144 B
    int*   hist  = (int*)(W + 2392064);            // 32768 B
    float* diffp = (float*)(W + 2424832);          // 32768 B
    int*   list  = (int*)(W + 2457600);            // 262144 B
    int*   cnt   = (int*)(W + 2719744);            // 8 B

    k_zero   <<<32,   256, 0, stream>>>(hist, diffp, cnt);
    k_enorm  <<<32,   256, 0, stream>>>(embed, enorm);
    k_prep_e <<<64,   256, 0, stream>>>(embed, ebf);
    k_score  <<<512,  256, 0, stream>>>(x, ebf, enorm, idx, list, cnt);
    k_rescore<<<256,  256, 0, stream>>>(x, embed, enorm, list, cnt, idx);
    k_emit   <<<256,  256, 0, stream>>>(idx, argf, hist);
    k_gather <<<8192, 256, 0, stream>>>(x, embed, idx, zq, diffp);
    k_final  <<<2,    256, 0, stream>>>(diffp, hist, diffs, ppls);
}

// Round 4
// 255.563 us; speedup vs baseline: 4.6366x; 2.0850x over previous
//
#include <hip/hip_runtime.h>
#include <hip/hip_bf16.h>
#include <math.h>

#define K_CB 2
#define DIM 128
#define NEMB 4096
#define HW 1024
#define NPK 32768
#define CCH 256
#define MARGIN 0.15f

typedef __attribute__((ext_vector_type(8))) _Float16 half8;
typedef __attribute__((ext_vector_type(4))) float f32x4;
typedef unsigned long long u64;

// ---------------- zero scratch (hist + diffp + cnt + slots) ----------------
__global__ void k_zero(int* __restrict__ hist, float* __restrict__ diffp,
                       int* __restrict__ cnt, u64* __restrict__ slots) {
    int t = blockIdx.x * blockDim.x + threadIdx.x;   // 65536 threads
    slots[t] = ~0ull;
    if (t < K_CB * NEMB) { hist[t] = 0; diffp[t] = 0.f; }
    if (t < K_CB) cnt[t] = 0;
}

// ---------------- ||e_j||^2 per (k,j) (fp32) ----------------
__global__ void k_enorm(const float* __restrict__ embed, float* __restrict__ enorm) {
    int g = blockIdx.x * blockDim.x + threadIdx.x;   // 0..8191
    int k = g >> 12;
    int j = g & (NEMB - 1);
    const float* e = embed + (size_t)k * DIM * NEMB + j;
    float s = 0.f;
#pragma unroll 8
    for (int d = 0; d < DIM; ++d) {
        float v = e[(size_t)d * NEMB];
        s = fmaf(v, v, s);
    }
    enorm[g] = s;
}

// ---------------- transpose embed -> fp16 [k][j][d] ----------------
__global__ void k_prep_e(const float* __restrict__ embed, ushort* __restrict__ ebf) {
    __shared__ ushort tile[DIM][130];
    const int k = blockIdx.x >> 5;
    const int j0 = (blockIdx.x & 31) * 128;
    const int t = threadIdx.x;
    const float* ek = embed + (size_t)k * DIM * NEMB;
    for (int i = 0; i < 64; ++i) {
        int idx = i * 256 + t;
        int d = idx >> 7, jj = idx & 127;
        float v = ek[(size_t)d * NEMB + j0 + jj];
        _Float16 h = (_Float16)v;
        tile[d][jj] = *(ushort*)&h;
    }
    __syncthreads();
    ushort* outk = ebf + ((size_t)k * NEMB + j0) * DIM;
    for (int i = 0; i < 64; ++i) {
        int idx = i * 256 + t;
        int jj = idx >> 7, d = idx & 127;
        outk[(size_t)jj * DIM + d] = tile[d][jj];
    }
}

// ---------------- coarse fp16 MFMA scoring + best/second argmin ----------------
// block: (k, n-tile of 128). 4 waves; wave w owns rows [w*32, w*32+32) and the
// FULL 128-col j-tile (single writer per row). LDS XOR-swizzled.
__launch_bounds__(256, 2)
__global__ void k_score(const float* __restrict__ x, const ushort* __restrict__ ebf,
                        const float* __restrict__ enorm, int* __restrict__ idxw,
                        int* __restrict__ list, int* __restrict__ cnt)
{
    __shared__ __align__(16) ushort As[128 * 128];
    __shared__ __align__(16) ushort Bs[128 * 128];
    const int blk = blockIdx.x;
    const int k = blk >> 8;
    const int n0 = (blk & 255) * 128;
    const int b = n0 >> 10;
    const int hw0 = n0 & (HW - 1);
    const int t = threadIdx.x;
    const int lane = t & 63;
    const int w = t >> 6;            // wave id: owns rows w*32..w*32+31
    const int l15 = lane & 15, l4 = lane >> 4;

    // ---- stage A once: transpose x[d][hw] -> As[n'][d] fp16, swizzled ----
    const float* xk = x + ((size_t)(b * CCH + k * DIM)) * HW + hw0;
    for (int i = 0; i < 64; ++i) {
        int idx = i * 256 + t;
        int d = idx >> 7, h = idx & 127;
        float v = xk[(size_t)d * HW + h];
        _Float16 hb = (_Float16)v;
        As[h * 128 + (d ^ ((h & 7) << 3))] = *(ushort*)&hb;
    }

    const ushort* ebk = ebf + (size_t)k * NEMB * DIM;
    const float* enk = enorm + k * NEMB;

    float best[8], second[8];
    int bestj[8];
#pragma unroll
    for (int i = 0; i < 8; ++i) { best[i] = 3.4e38f; second[i] = 3.4e38f; bestj[i] = 0; }

    for (int jt = 0; jt < 32; ++jt) {
        const int j0 = jt * 128;
        __syncthreads();   // previous tile's reads done (also covers A-stage at jt=0)
        // ---- stage B tile [j'][d] via global_load_lds, inverse-swizzled source ----
#pragma unroll
        for (int it = 0; it < 8; ++it) {
            int lin = (it * 256 + t) * 16;         // dest byte in Bs (linear)
            int row = lin >> 8;                    // j'
            int col = lin & 255;
            int src = row * 256 + (col ^ ((row & 7) << 4));
            const char* g = (const char*)ebk + (size_t)j0 * 256 + src;
            char* lds = (char*)(&Bs[0]) + (it * 256 + (t & ~63)) * 16;  // wave-uniform base
            __builtin_amdgcn_global_load_lds(
                (const __attribute__((address_space(1))) unsigned int*)g,
                (__attribute__((address_space(3))) unsigned int*)lds, 16, 0, 0);
        }
        __syncthreads();

        // ---- compute this wave's 32 rows x 128 cols ----
        f32x4 acc[2][8];
#pragma unroll
        for (int mf = 0; mf < 2; ++mf)
#pragma unroll
            for (int jf = 0; jf < 8; ++jf) acc[mf][jf] = (f32x4){0.f, 0.f, 0.f, 0.f};

#pragma unroll
        for (int kk = 0; kk < 4; ++kk) {
            half8 a[2], bb[8];
#pragma unroll
            for (int mf = 0; mf < 2; ++mf) {
                int row = w * 32 + mf * 16 + l15;
                int ci = (kk * 32 + l4 * 8) ^ ((row & 7) << 3);
                a[mf] = *(const half8*)&As[row * 128 + ci];
            }
#pragma unroll
            for (int jf = 0; jf < 8; ++jf) {
                int row = jf * 16 + l15;
                int ci = (kk * 32 + l4 * 8) ^ ((row & 7) << 3);
                bb[jf] = *(const half8*)&Bs[row * 128 + ci];
            }
#pragma unroll
            for (int mf = 0; mf < 2; ++mf)
#pragma unroll
                for (int jf = 0; jf < 8; ++jf)
                    acc[mf][jf] = __builtin_amdgcn_mfma_f32_16x16x32_f16(a[mf], bb[jf], acc[mf][jf], 0, 0, 0);
        }

        // ---- epilogue: score + best/second tracking over the FULL j-tile ----
#pragma unroll
        for (int jf = 0; jf < 8; ++jf) {
            const int j = j0 + jf * 16 + l15;
            const float en = enk[j];
#pragma unroll
            for (int mf = 0; mf < 2; ++mf) {
#pragma unroll
                for (int r = 0; r < 4; ++r) {
                    float s = fmaf(-2.f, acc[mf][jf][r], en);
                    int ti = mf * 4 + r;
                    float mx = fmaxf(s, best[ti]);
                    second[ti] = fminf(second[ti], mx);
                    bool lt = s < best[ti];
                    bestj[ti] = lt ? j : bestj[ti];
                    best[ti] = lt ? s : best[ti];
                }
            }
        }
    }

    // ---- merge across the 16 j-lanes (same rows: same w, same l4) ----
#pragma unroll
    for (int off = 1; off < 16; off <<= 1) {
#pragma unroll
        for (int ti = 0; ti < 8; ++ti) {
            float ob = __shfl_xor(best[ti], off);
            float os = __shfl_xor(second[ti], off);
            int oj = __shfl_xor(bestj[ti], off);
            float ns = fminf(fmaxf(best[ti], ob), fminf(second[ti], os));
            bool take = (ob < best[ti]) || (ob == best[ti] && oj < bestj[ti]);
            bestj[ti] = take ? oj : bestj[ti];
            best[ti] = fminf(best[ti], ob);
            second[ti] = ns;
        }
    }
    if (l15 == 0) {
#pragma unroll
        for (int ti = 0; ti < 8; ++ti) {
            int mf = ti >> 2, r = ti & 3;
            int n = n0 + w * 32 + mf * 16 + l4 * 4 + r;
            int gidx = k * NPK + n;
            idxw[gidx] = bestj[ti];
            if (second[ti] - best[ti] < MARGIN) {
                int p = atomicAdd(&cnt[k], 1);
                list[k * NPK + p] = gidx;
            }
        }
    }
}

// ---------------- exact fp32 rescore: (8-row chunk) x (512-j slab) items ----------------
// Merge via packed (ordered-score || j) u64 atomicMin into per-flagged-row slots.
__launch_bounds__(256, 4)
__global__ void k_rescore(const float* __restrict__ x, const float* __restrict__ embed,
                          const float* __restrict__ enorm, const int* __restrict__ list,
                          const int* __restrict__ cnt, u64* __restrict__ slots)
{
    __shared__ float xr[8][128];
    __shared__ u64 part[4][8];
    const int t = threadIdx.x;
    const int lane = t & 63, wv = t >> 6;
    const int c0 = cnt[0], c1 = cnt[1];
    const int items0 = ((c0 + 7) >> 3) * 8;
    const int items1 = ((c1 + 7) >> 3) * 8;
    const int total = items0 + items1;

    for (int item = blockIdx.x; item < total; item += gridDim.x) {
        int k, c, s, ck;
        if (item < items0) { k = 0; c = item >> 3; s = item & 7; ck = c0; }
        else { int it = item - items0; k = 1; c = it >> 3; s = it & 7; ck = c1; }
        const int base = c * 8;
        const int cn = min(8, ck - base);
        __syncthreads();   // xr / part reuse safety
        for (int ii = t; ii < cn * 128; ii += 256) {
            int ri = ii >> 7, d = ii & 127;
            int gidx = list[k * NPK + base + ri];
            int n = gidx & (NPK - 1);
            int bb = n >> 10, hw = n & 1023;
            xr[ri][d] = x[((size_t)(bb * CCH + k * DIM + d)) * HW + hw];
        }
        __syncthreads();

        u64 key[8];
#pragma unroll
        for (int ri = 0; ri < 8; ++ri) key[ri] = ~0ull;
        const float* ek = embed + (size_t)k * DIM * NEMB;
#pragma unroll
        for (int jj = 0; jj < 2; ++jj) {
            const int j = s * 512 + jj * 256 + t;
            float dot[8];
#pragma unroll
            for (int ri = 0; ri < 8; ++ri) dot[ri] = 0.f;
            for (int d = 0; d < DIM; ++d) {
                float ev = ek[(size_t)d * NEMB + j];
#pragma unroll
                for (int ri = 0; ri < 8; ++ri) dot[ri] = fmaf(xr[ri][d], ev, dot[ri]);
            }
            const float en = enorm[k * NEMB + j];
#pragma unroll
            for (int ri = 0; ri < 8; ++ri) {
                float sc = fmaf(-2.f, dot[ri], en);
                unsigned int bits = __float_as_uint(sc);
                unsigned int u = (sc >= 0.f) ? (bits | 0x80000000u) : ~bits;
                u64 kk = ((u64)u << 32) | (unsigned int)j;
                key[ri] = kk < key[ri] ? kk : key[ri];
            }
        }
        // wave-level u64 min reduce
#pragma unroll
        for (int off = 32; off; off >>= 1) {
#pragma unroll
            for (int ri = 0; ri < 8; ++ri) {
                u64 o = __shfl_xor(key[ri], off);
                key[ri] = o < key[ri] ? o : key[ri];
            }
        }
        if (lane == 0) {
#pragma unroll
            for (int ri = 0; ri < 8; ++ri) part[wv][ri] = key[ri];
        }
        __syncthreads();
        if (t < 32) {
            int ri = t >> 2, w2 = t & 3;
            u64 kk = part[w2][ri];
            u64 o = __shfl_xor(kk, 1); kk = o < kk ? o : kk;
            o = __shfl_xor(kk, 2);     kk = o < kk ? o : kk;
            if (w2 == 0 && ri < cn)
                atomicMin(&slots[k * NPK + base + ri], kk);
        }
    }
}

// ---------------- write rescored winners back into idx ----------------
__global__ void k_fixup(const int* __restrict__ list, const int* __restrict__ cnt,
                        const u64* __restrict__ slots, int* __restrict__ idxw) {
    int g = blockIdx.x * 256 + threadIdx.x;   // 0..32767
#pragma unroll
    for (int k = 0; k < K_CB; ++k)
        if (g < cnt[k])
            idxw[list[k * NPK + g]] = (int)(slots[k * NPK + g] & 0xFFFFFFFFu);
}

// ---------------- idx -> argf float + histogram ----------------
__global__ void k_emit(const int* __restrict__ idxw, float* __restrict__ argf, int* __restrict__ hist) {
    int g = blockIdx.x * 256 + threadIdx.x;
    int j = idxw[g];
    argf[g] = (float)j;
    atomicAdd(&hist[(g >> 15) * NEMB + j], 1);
}

// ---------------- gather z_q + diff partial sums ----------------
__global__ void k_gather(const float* __restrict__ x, const float* __restrict__ embed,
                         const int* __restrict__ idx, float* __restrict__ zq,
                         float* __restrict__ diffp)
{
    const int blk = blockIdx.x;           // k*4096 + b*128 + d
    const int k = blk >> 12;
    const int b = (blk >> 7) & 31;
    const int d = blk & 127;
    const float* erow = embed + ((size_t)k * DIM + d) * NEMB;
    const int* idxr = idx + k * NPK + b * HW;
    const size_t row = ((size_t)b * CCH + (size_t)k * DIM + d) * HW;
    const float* xr = x + row;
    float* zr = zq + row;
    const int t = threadIdx.x;
    float s = 0.f;
    for (int h = t; h < HW; h += 256) {
        int j = idxr[h];
        float q = erow[j];
        float xv = xr[h];
        float df = q - xv;
        s = fmaf(df, df, s);
        zr[h] = q;
    }
    __shared__ float red[256];
    red[t] = s;
    __syncthreads();
    for (int off = 128; off > 0; off >>= 1) {
        if (t < off) red[t] += red[t + off];
        __syncthreads();
    }
    if (t == 0) diffp[blk] = red[0];
}

// ---------------- finalize diffs + perplexity ----------------
__global__ void k_final(const float* __restrict__ diffp, const int* __restrict__ hist,
                        float* __restrict__ diffs, float* __restrict__ ppls)
{
    const int k = blockIdx.x;
    const int t = threadIdx.x;
    __shared__ float red[256];
    float s = 0.f;
    for (int i = t; i < NEMB; i += 256) s += diffp[k * NEMB + i];
    red[t] = s;
    __syncthreads();
    for (int off = 128; off > 0; off >>= 1) {
        if (t < off) red[t] += red[t + off];
        __syncthreads();
    }
    if (t == 0) diffs[k] = red[0] / (float)((size_t)NPK * DIM);
    __syncthreads();
    float s2 = 0.f;
    for (int i = t; i < NEMB; i += 256) {
        float p = (float)hist[k * NEMB + i] * (1.0f / (float)NPK);
        s2 += p * logf(p + 1e-10f);
    }
    red[t] = s2;
    __syncthreads();
    for (int off = 128; off > 0; off >>= 1) {
        if (t < off) red[t] += red[t + off];
        __syncthreads();
    }
    if (t == 0) ppls[k] = expf(-red[0]);
}

extern "C" void kernel_launch(void* const* d_in, const int* in_sizes, int n_in,
                              void* d_out, int out_size, void* d_ws, size_t ws_size,
                              hipStream_t stream) {
    const float* x = (const float*)d_in[0];       // [32,256,32,32]
    const float* embed = (const float*)d_in[1];   // [2,128,4096]
    float* out = (float*)d_out;
    float* zq    = out;                 // 8388608
    float* diffs = out + 8388608;       // 2
    float* argf  = out + 8388610;       // 65536 ([K,B,H,W] as float)
    float* ppls  = out + 8454146;       // 2

    char* W = (char*)d_ws;
    ushort* ebf  = (ushort*)W;                     // 2,097,152 B : embedT fp16 [2][4096][128]
    float* enorm = (float*)(W + 2097152);          // 32768 B
    int*   idx   = (int*)(W + 2129920);            // 262144 B
    int*   hist  = (int*)(W + 2392064);            // 32768 B
    float* diffp = (float*)(W + 2424832);          // 32768 B
    int*   list  = (int*)(W + 2457600);            // 262144 B
    int*   cnt   = (int*)(W + 2719744);            // 64 B (padded)
    u64*   slots = (u64*)(W + 2719808);            // 524288 B -> end ~3.24 MB

    k_zero   <<<256,  256, 0, stream>>>(hist, diffp, cnt, slots);
    k_enorm  <<<32,   256, 0, stream>>>(embed, enorm);
    k_prep_e <<<64,   256, 0, stream>>>(embed, ebf);
    k_score  <<<512,  256, 0, stream>>>(x, ebf, enorm, idx, list, cnt);
    k_rescore<<<2048, 256, 0, stream>>>(x, embed, enorm, list, cnt, slots);
    k_fixup  <<<128,  256, 0, stream>>>(list, cnt, slots, idx);
    k_emit   <<<256,  256, 0, stream>>>(idx, argf, hist);
    k_gather <<<8192, 256, 0, stream>>>(x, embed, idx, zq, diffp);
    k_final  <<<2,    256, 0, stream>>>(diffp, hist, diffs, ppls);
}